// Round 14
// baseline (298.785 us; speedup 1.0000x reference)
//
#include <hip/hip_runtime.h>

#define DIM 64
#define CHUNK 8192      // edges per partition block (64KB LDS stage in p1c)
#define MAXNB 512       // max coarse buckets (N <= 524288 with BSHIFT=10)
#define BSHIFT 10
#define RPB 1024        // rows per bucket (1 << BSHIFT)
#define PADMASK 7       // rows padded to multiple of 8
#define CONVB 768       // conv blocks appended to p1a grid (sepEmb mode)

union H8 { uint4 u; _Float16 h[8]; };
union H4 { uint2 u; _Float16 h[4]; };

// inclusive block scan over 256 per-thread values; sh[255] = total after call
__device__ __forceinline__ int blockScan256(int v, int* sh) {
    int t = threadIdx.x;
    sh[t] = v;
    __syncthreads();
    for (int off = 1; off < 256; off <<= 1) {
        int x = (t >= off) ? sh[t - off] : 0;
        __syncthreads();
        sh[t] += x;
        __syncthreads();
    }
    return sh[t];
}

__device__ __forceinline__ void convBody(const float* __restrict__ u,
                                         const float* __restrict__ it,
                                         int nu, int ntot, unsigned short* __restrict__ o,
                                         int start, int stride) {
    int n8 = ntot >> 3;
    for (int t = start; t < n8; t += stride) {
        int e = t * 8;
        const float* src = (e < nu) ? (u + e) : (it + (e - nu));
        float4 x = *(const float4*)src;
        float4 y = *(const float4*)(src + 4);
        H8 v;
        v.h[0] = (_Float16)x.x; v.h[1] = (_Float16)x.y;
        v.h[2] = (_Float16)x.z; v.h[3] = (_Float16)x.w;
        v.h[4] = (_Float16)y.x; v.h[5] = (_Float16)y.y;
        v.h[6] = (_Float16)y.z; v.h[7] = (_Float16)y.w;
        ((uint4*)o)[t] = v.u;
    }
}

// ---------------- P1a (coarse hist) + fused f32->f16 conv (sepEmb mode) ----------------

__global__ void p1a_conv(const int* __restrict__ row, int E, int NB,
                         int* __restrict__ counts,
                         const float* __restrict__ u, const float* __restrict__ it,
                         int nu, int ntot, unsigned short* __restrict__ o, int NBLK) {
    __shared__ int h[MAXNB];
    int blk = blockIdx.x;
    if (blk < NBLK) {
        for (int b = threadIdx.x; b < NB; b += 256) h[b] = 0;
        __syncthreads();
        int base = blk * CHUNK;
        int end = min(base + CHUNK, E);
        int vend = base + ((end - base) & ~3);
        for (int i = base + threadIdx.x * 4; i < vend; i += 1024) {
            int4 r = *(const int4*)(row + i);
            atomicAdd(&h[r.x >> BSHIFT], 1);
            atomicAdd(&h[r.y >> BSHIFT], 1);
            atomicAdd(&h[r.z >> BSHIFT], 1);
            atomicAdd(&h[r.w >> BSHIFT], 1);
        }
        for (int i = vend + threadIdx.x; i < end; i += 256) atomicAdd(&h[row[i] >> BSHIFT], 1);
        __syncthreads();
        for (int b = threadIdx.x; b < NB; b += 256) counts[(size_t)blk * NB + b] = h[b];
    } else {
        int nConv = gridDim.x - NBLK;
        convBody(u, it, nu, ntot, o, (blk - NBLK) * 256 + threadIdx.x, nConv * 256);
    }
}

// fallback standalone conv (overlay layout)
__global__ void conv2_k(const float* __restrict__ u, const float* __restrict__ it,
                        int nu, int ntot, unsigned short* __restrict__ o) {
    convBody(u, it, nu, ntot, o, blockIdx.x * blockDim.x + threadIdx.x,
             gridDim.x * blockDim.x);
}

__global__ void p1b_scan(int* __restrict__ counts, int NBLK, int NB,
                         int* __restrict__ bucketTotal) {
    int b = blockIdx.x, t = threadIdx.x;
    __shared__ int sh[256];
    int v[8];
    int run = 0;
#pragma unroll
    for (int i = 0; i < 8; i++) {
        int idx = t * 8 + i;
        int c = (idx < NBLK) ? counts[(size_t)idx * NB + b] : 0;
        v[i] = run;  // exclusive within thread
        run += c;
    }
    int inc = blockScan256(run, sh);
    int excl = inc - run;
#pragma unroll
    for (int i = 0; i < 8; i++) {
        int idx = t * 8 + i;
        if (idx < NBLK) counts[(size_t)idx * NB + b] = v[i] + excl;
    }
    if (t == 255) bucketTotal[b] = sh[255];
}

// P1c: scatter into 64KB LDS stage grouped by bucket, then COALESCED writeback of each
// bucket's contiguous run (bdata + 2B rowlow sidecar). bucketStart computed locally
// from bucketTotal (no p_scan_tot kernel). raw counts from scanned counts matrix.
__global__ void p1c_scatter(const int* __restrict__ row, const int* __restrict__ col,
                            const float* __restrict__ vals, int E, int NB, int NBLK,
                            const int* __restrict__ counts, const int* __restrict__ bucketTotal,
                            int2* __restrict__ bdata, unsigned short* __restrict__ rowlow16) {
    __shared__ int2 stage[CHUNK];
    __shared__ int cur[MAXNB];
    __shared__ int rawcnt[MAXNB];
    __shared__ int bst[MAXNB];
    __shared__ int sh[256];
    int blk = blockIdx.x, t = threadIdx.x;
    int base = blk * CHUNK;
    int end = min(base + CHUNK, E);
    // scan 1: raw per-(chunk,bucket) counts -> LDS stage offsets
    int v[2];
    int run = 0;
#pragma unroll
    for (int i = 0; i < 2; i++) {
        int b = t * 2 + i;
        int c = 0;
        if (b < NB) {
            int s0c = counts[(size_t)blk * NB + b];
            int s1c = (blk + 1 < NBLK) ? counts[(size_t)(blk + 1) * NB + b] : bucketTotal[b];
            c = s1c - s0c;
            rawcnt[b] = c;
        }
        v[i] = run;
        run += c;
    }
    int inc = blockScan256(run, sh);
    int excl = inc - run;
#pragma unroll
    for (int i = 0; i < 2; i++) {
        int b = t * 2 + i;
        if (b < NB) cur[b] = excl + v[i];
    }
    // scan 2: bucketTotal -> bucketStart (local)
    int w[2];
    int run2 = 0;
#pragma unroll
    for (int i = 0; i < 2; i++) {
        int b = t * 2 + i;
        int c = (b < NB) ? bucketTotal[b] : 0;
        w[i] = run2;
        run2 += c;
    }
    int inc2 = blockScan256(run2, sh);
    int excl2 = inc2 - run2;
#pragma unroll
    for (int i = 0; i < 2; i++) {
        int b = t * 2 + i;
        if (b < NB) bst[b] = excl2 + w[i];
    }
    __syncthreads();
    // scatter edges into the LDS stage (bucket-grouped)
    int vend = base + ((end - base) & ~3);
    for (int i = base + t * 4; i < vend; i += 1024) {
        int4 r = *(const int4*)(row + i);
        int4 c = *(const int4*)(col + i);
        float4 wv4 = *(const float4*)(vals + i);
        int p0 = atomicAdd(&cur[r.x >> BSHIFT], 1);
        int p1 = atomicAdd(&cur[r.y >> BSHIFT], 1);
        int p2 = atomicAdd(&cur[r.z >> BSHIFT], 1);
        int p3 = atomicAdd(&cur[r.w >> BSHIFT], 1);
        stage[p0] = make_int2(((r.x & (RPB - 1)) << 20) | c.x, __float_as_int(wv4.x));
        stage[p1] = make_int2(((r.y & (RPB - 1)) << 20) | c.y, __float_as_int(wv4.y));
        stage[p2] = make_int2(((r.z & (RPB - 1)) << 20) | c.z, __float_as_int(wv4.z));
        stage[p3] = make_int2(((r.w & (RPB - 1)) << 20) | c.w, __float_as_int(wv4.w));
    }
    for (int i = vend + t; i < end; i += 256) {
        int r = row[i];
        int p = atomicAdd(&cur[r >> BSHIFT], 1);
        stage[p] = make_int2(((r & (RPB - 1)) << 20) | col[i], __float_as_int(vals[i]));
    }
    __syncthreads();
    // coalesced writeback: wave per bucket round-robin; contiguous run in LDS & global
    int wv = t >> 6, lane = t & 63;
    for (int b = wv; b < NB; b += 4) {
        int cnt = rawcnt[b];
        int lo = cur[b] - cnt;
        int gb = bst[b] + counts[(size_t)blk * NB + b];
        for (int i = lane; i < cnt; i += 64) {
            int2 e = stage[lo + i];
            bdata[gb + i] = e;
            rowlow16[gb + i] = (unsigned short)((e.x >> 20) & (RPB - 1));
        }
    }
}

// P2: per-bucket regroup by exact row into PADDED rows (pads = colOff 0, val 0).
// Hist pass reads the 2B rowlow sidecar (not 8B bdata). bucketStart computed locally.
__global__ void p2_group(const int2* __restrict__ bdata,
                         const unsigned short* __restrict__ rowlow16,
                         const int* __restrict__ bucketTotal,
                         int NB, int N, int padSlop,
                         int* __restrict__ rowStart, int* __restrict__ rowLen,
                         int2* __restrict__ pairs) {
    __shared__ int hist[RPB];
    __shared__ int sh[256];
    __shared__ int cur[RPB];
    __shared__ int bst[MAXNB];
    int b = blockIdx.x, t = threadIdx.x;
    // local exclusive scan of bucketTotal -> bst
    int w[2];
    int run2 = 0;
#pragma unroll
    for (int i = 0; i < 2; i++) {
        int bb = t * 2 + i;
        int c = (bb < NB) ? bucketTotal[bb] : 0;
        w[i] = run2;
        run2 += c;
    }
    int inc2 = blockScan256(run2, sh);
    int excl2 = inc2 - run2;
#pragma unroll
    for (int i = 0; i < 2; i++) {
        int bb = t * 2 + i;
        if (bb < NB) bst[bb] = excl2 + w[i];
    }
    for (int i = t; i < RPB; i += 256) hist[i] = 0;
    __syncthreads();
    int s0 = bst[b];
    int s1 = s0 + bucketTotal[b];
    int pbase = s0 + b * padSlop;
    for (int i = s0 + t; i < s1; i += 256)
        atomicAdd(&hist[rowlow16[i]], 1);
    __syncthreads();
    int v[4];
    int run = 0;
#pragma unroll
    for (int i = 0; i < 4; i++) {
        int h = hist[t * 4 + i];
        int hp = (h + PADMASK) & ~PADMASK;
        v[i] = run;  // exclusive within thread
        run += hp;
    }
    int inc = blockScan256(run, sh);
    int excl = inc - run;
#pragma unroll
    for (int i = 0; i < 4; i++) {
        int r = (b << BSHIFT) + t * 4 + i;
        int st = excl + v[i];
        if (r < N) {
            int h = hist[t * 4 + i];
            rowStart[r] = pbase + st;
            rowLen[r] = (h + PADMASK) & ~PADMASK;
        }
        cur[t * 4 + i] = st;
    }
    __syncthreads();
    for (int i = s0 + t; i < s1; i += 256) {
        int2 e = bdata[i];
        int rl = (e.x >> 20) & (RPB - 1);
        int pos = atomicAdd(&cur[rl], 1);
        pairs[pbase + pos] = make_int2((e.x & 0xFFFFF) << 7, e.y);
    }
    __syncthreads();
#pragma unroll
    for (int i = 0; i < 4; i++) {
        int h = hist[t * 4 + i];
        int hp = (h + PADMASK) & ~PADMASK;
        int st = excl + v[i];
        for (int p = st + h; p < st + hp; p++)
            pairs[pbase + p] = make_int2(0, 0);
    }
}

// ---------------- layer-1 SpMM: wave per row, 8 edge-groups x 8 dim-octs ----------------
// f16 storage + (float)h * v accumulation -> v_fma_mix_f32 (no unpack ops).

__global__ void spmm1_k(const unsigned short* __restrict__ emb16,
                        const int* __restrict__ rowStart, const int* __restrict__ rowLen,
                        const int2* __restrict__ pairs,
                        int n_total, unsigned short* __restrict__ e1) {
    int wave = (blockIdx.x * blockDim.x + threadIdx.x) >> 6;
    int lane = threadIdx.x & 63;
    if (wave >= n_total) return;
    int eg = lane >> 3, dp = lane & 7;
    unsigned off0 = dp * 16u;
    const char* base = (const char*)emb16;
    int len = rowLen[wave];
    const int2* pp = pairs + rowStart[wave];
    float aA[8] = {0.f, 0.f, 0.f, 0.f, 0.f, 0.f, 0.f, 0.f};
    float aB[8] = {0.f, 0.f, 0.f, 0.f, 0.f, 0.f, 0.f, 0.f};
    int k = 0;
    for (; k + 16 <= len; k += 16) {
        int4 q = *(const int4*)(pp + k + 2 * eg);
        H8 g0, g1;
        g0.u = *(const uint4*)(base + ((unsigned)q.x + off0));
        g1.u = *(const uint4*)(base + ((unsigned)q.z + off0));
        float v0 = __int_as_float(q.y), v1 = __int_as_float(q.w);
#pragma unroll
        for (int i = 0; i < 8; i++) aA[i] += (float)g0.h[i] * v0;
#pragma unroll
        for (int i = 0; i < 8; i++) aB[i] += (float)g1.h[i] * v1;
    }
    if (k < len) {
        int2 p = pp[k + eg];
        H8 g0;
        g0.u = *(const uint4*)(base + ((unsigned)p.x + off0));
        float v0 = __int_as_float(p.y);
#pragma unroll
        for (int i = 0; i < 8; i++) aA[i] += (float)g0.h[i] * v0;
    }
    float s[8];
#pragma unroll
    for (int i = 0; i < 8; i++) s[i] = aA[i] + aB[i];
#pragma unroll
    for (int m = 8; m <= 32; m <<= 1) {
#pragma unroll
        for (int i = 0; i < 8; i++) s[i] += __shfl_xor(s[i], m);
    }
    if (eg == 0) {
        H8 o;
#pragma unroll
        for (int i = 0; i < 8; i++) o.h[i] = (_Float16)s[i];
        *(uint4*)(e1 + (size_t)wave * DIM + dp * 8) = o.u;
    }
}

// ---------------- fused layer-2 + gather + dot epilogue ----------------

__global__ void final_k(const float* __restrict__ emb_user, const float* __restrict__ emb_item,
                        int n_user, const unsigned short* __restrict__ e1,
                        const int* __restrict__ rowStart, const int* __restrict__ rowLen,
                        const int2* __restrict__ pairs,
                        const int* __restrict__ u_nodes, const int* __restrict__ p_nodes,
                        const int* __restrict__ n_nodes, int B, float* __restrict__ out) {
    int wave = (blockIdx.x * blockDim.x + threadIdx.x) >> 6;
    int lane = threadIdx.x & 63;
    if (wave >= B) return;
    int eg = lane >> 4, dp = lane & 15;
    unsigned off0 = dp * 8u;
    const char* base = (const char*)e1;
    int nid[3] = {u_nodes[wave], p_nodes[wave], n_nodes[wave]};
    float l[3][4];
#pragma unroll
    for (int j = 0; j < 3; j++) {
        int r = nid[j];
        const float* base0 = (r < n_user) ? (emb_user + (size_t)r * DIM)
                                          : (emb_item + (size_t)(r - n_user) * DIM);
        float4 l0 = *(const float4*)(base0 + dp * 4);
        H4 t1;
        t1.u = *(const uint2*)(e1 + (size_t)r * DIM + dp * 4);
        float acc[4];
        acc[0] = l0.x + (float)t1.h[0];
        acc[1] = l0.y + (float)t1.h[1];
        acc[2] = l0.z + (float)t1.h[2];
        acc[3] = l0.w + (float)t1.h[3];
        int len = rowLen[r];
        const int2* pp = pairs + rowStart[r];
        float a0[4] = {0.f, 0.f, 0.f, 0.f}, a1[4] = {0.f, 0.f, 0.f, 0.f};
        float a2[4] = {0.f, 0.f, 0.f, 0.f}, a3[4] = {0.f, 0.f, 0.f, 0.f};
        int k = 0;
        for (; k + 16 <= len; k += 16) {
            int4 q0 = *(const int4*)(pp + k + 2 * eg);
            int4 q1 = *(const int4*)(pp + k + 8 + 2 * eg);
            H4 g0, g1, g2, g3;
            g0.u = *(const uint2*)(base + ((unsigned)q0.x + off0));
            g1.u = *(const uint2*)(base + ((unsigned)q0.z + off0));
            g2.u = *(const uint2*)(base + ((unsigned)q1.x + off0));
            g3.u = *(const uint2*)(base + ((unsigned)q1.z + off0));
            float v0 = __int_as_float(q0.y), v1 = __int_as_float(q0.w);
            float v2 = __int_as_float(q1.y), v3 = __int_as_float(q1.w);
#pragma unroll
            for (int i = 0; i < 4; i++) {
                a0[i] += (float)g0.h[i] * v0;
                a1[i] += (float)g1.h[i] * v1;
                a2[i] += (float)g2.h[i] * v2;
                a3[i] += (float)g3.h[i] * v3;
            }
        }
        for (; k < len; k += 8) {
            int4 q0 = *(const int4*)(pp + k + 2 * eg);
            H4 g0, g1;
            g0.u = *(const uint2*)(base + ((unsigned)q0.x + off0));
            g1.u = *(const uint2*)(base + ((unsigned)q0.z + off0));
            float v0 = __int_as_float(q0.y), v1 = __int_as_float(q0.w);
#pragma unroll
            for (int i = 0; i < 4; i++) {
                a0[i] += (float)g0.h[i] * v0;
                a1[i] += (float)g1.h[i] * v1;
            }
        }
        float s[4];
#pragma unroll
        for (int i = 0; i < 4; i++) s[i] = (a0[i] + a1[i]) + (a2[i] + a3[i]);
#pragma unroll
        for (int i = 0; i < 4; i++) {
            s[i] += __shfl_xor(s[i], 16);
            s[i] += __shfl_xor(s[i], 32);
        }
#pragma unroll
        for (int i = 0; i < 4; i++) l[j][i] = (acc[i] + s[i]) * (1.0f / 3.0f);
    }
    float ps = l[0][0] * l[1][0] + l[0][1] * l[1][1] + l[0][2] * l[1][2] + l[0][3] * l[1][3];
    float ns = l[0][0] * l[2][0] + l[0][1] * l[2][1] + l[0][2] * l[2][2] + l[0][3] * l[2][3];
    ps += __shfl_xor(ps, 1); ns += __shfl_xor(ns, 1);
    ps += __shfl_xor(ps, 2); ns += __shfl_xor(ns, 2);
    ps += __shfl_xor(ps, 4); ns += __shfl_xor(ns, 4);
    ps += __shfl_xor(ps, 8); ns += __shfl_xor(ns, 8);
    if (lane == 0) {
        out[wave] = ps;
        out[B + wave] = ns;
    }
}

extern "C" void kernel_launch(void* const* d_in, const int* in_sizes, int n_in,
                              void* d_out, int out_size, void* d_ws, size_t ws_size,
                              hipStream_t stream) {
    const float* emb_user = (const float*)d_in[0];
    const float* emb_item = (const float*)d_in[1];
    const float* gvals    = (const float*)d_in[2];
    const int*   grow     = (const int*)d_in[3];
    const int*   gcol     = (const int*)d_in[4];
    const int*   unodes   = (const int*)d_in[5];
    const int*   pnodes   = (const int*)d_in[6];
    const int*   nnodes   = (const int*)d_in[7];
    float* out = (float*)d_out;

    int n_user = in_sizes[0] / DIM;
    int n_item = in_sizes[1] / DIM;
    int N = n_user + n_item;
    int E = in_sizes[2];
    int B = in_sizes[5];
    int NB = (N + RPB - 1) >> BSHIFT;
    int NBLK = (E + CHUNK - 1) / CHUNK;
    int padSlop = RPB * PADMASK;

    auto align256 = [](size_t x) { return (x + 255) & ~(size_t)255; };
    size_t embBytes = (size_t)N * DIM * 2;
    size_t countsBytes = (size_t)NBLK * NB * 4;
    size_t bdataBytes = (size_t)E * 8;
    size_t rowlowBytes = (size_t)E * 2;
    size_t regionABytes = countsBytes > embBytes ? countsBytes : embBytes;  // counts / e1
    size_t pairsBytes = ((size_t)E + (size_t)NB * padSlop) * 8;
    size_t fixedBytes = align256((size_t)N * 4) * 2 + align256((size_t)MAXNB * 4) +
                        align256(pairsBytes) + align256(rowlowBytes) +
                        align256(regionABytes);
    // preferred: emb16 separate from bdata -> conv fused into p1a (before bdata exists)
    bool sepEmb = fixedBytes + align256(bdataBytes) + align256(embBytes) <= ws_size;

    char* ws = (char*)d_ws;
    size_t off = 0;
    auto alloc = [&](size_t bytes) -> void* {
        void* p = ws + off;
        off = (off + bytes + 255) & ~(size_t)255;
        return p;
    };
    int*  rowStart    = (int*)alloc((size_t)N * 4);
    int*  rowLen      = (int*)alloc((size_t)N * 4);
    int*  bucketTotal = (int*)alloc((size_t)MAXNB * 4);
    int2* pairs       = (int2*)alloc(pairsBytes);
    unsigned short* rowlow16 = (unsigned short*)alloc(rowlowBytes);
    int2* bdata;
    unsigned short* emb16;
    if (sepEmb) {
        bdata = (int2*)alloc(bdataBytes);
        emb16 = (unsigned short*)alloc(embBytes);
    } else {
        char* regionB = (char*)alloc(bdataBytes > embBytes ? bdataBytes : embBytes);
        bdata = (int2*)regionB;            // dead after p2
        emb16 = (unsigned short*)regionB;  // written after p2 (overlay)
    }
    char* regionA = (char*)alloc(regionABytes);
    int*            counts = (int*)regionA;  // dead after p1c
    unsigned short* e1     = (unsigned short*)regionA;
    (void)n_in; (void)out_size;

    // CSR build via two-level counting sort (no global atomics, no 1-block scan kernel)
    int nConv = sepEmb ? CONVB : 0;
    p1a_conv<<<NBLK + nConv, 256, 0, stream>>>(grow, E, NB, counts,
                                               emb_user, emb_item, n_user * DIM, N * DIM,
                                               emb16, NBLK);
    p1b_scan<<<NB, 256, 0, stream>>>(counts, NBLK, NB, bucketTotal);
    p1c_scatter<<<NBLK, 256, 0, stream>>>(grow, gcol, gvals, E, NB, NBLK,
                                          counts, bucketTotal, bdata, rowlow16);
    p2_group<<<NB, 256, 0, stream>>>(bdata, rowlow16, bucketTotal, NB, N, padSlop,
                                     rowStart, rowLen, pairs);
    if (!sepEmb)  // overlay layout: pack after bdata is dead
        conv2_k<<<2048, 256, 0, stream>>>(emb_user, emb_item, n_user * DIM, N * DIM, emb16);

    // layer-1 SpMM over all rows (e1 overlays dead counts)
    spmm1_k<<<(N + 3) / 4, 256, 0, stream>>>(emb16, rowStart, rowLen, pairs, N, e1);
    // fused layer-2 + gather + dots
    final_k<<<(B + 3) / 4, 256, 0, stream>>>(emb_user, emb_item, n_user, e1,
                                             rowStart, rowLen, pairs,
                                             unodes, pnodes, nnodes, B, out);
}

// Round 15
// 293.045 us; speedup vs baseline: 1.0196x; 1.0196x over previous
//
#include <hip/hip_runtime.h>

#define DIM 64
#define CHUNK 8192      // edges per partition block (64KB LDS stage in p1c)
#define MAXNB 512       // max coarse buckets (N <= 524288 with BSHIFT=10)
#define BSHIFT 10
#define RPB 1024        // rows per bucket (1 << BSHIFT)
#define PADMASK 7       // rows padded to multiple of 8
#define CONVB 768       // conv blocks appended to p1a grid (sepEmb mode)

union H8 { uint4 u; _Float16 h[8]; };
union H4 { uint2 u; _Float16 h[4]; };

// inclusive block scan over 256 per-thread values; sh[255] = total after call
__device__ __forceinline__ int blockScan256(int v, int* sh) {
    int t = threadIdx.x;
    sh[t] = v;
    __syncthreads();
    for (int off = 1; off < 256; off <<= 1) {
        int x = (t >= off) ? sh[t - off] : 0;
        __syncthreads();
        sh[t] += x;
        __syncthreads();
    }
    return sh[t];
}

__device__ __forceinline__ void convBody(const float* __restrict__ u,
                                         const float* __restrict__ it,
                                         int nu, int ntot, unsigned short* __restrict__ o,
                                         int start, int stride) {
    int n8 = ntot >> 3;
    for (int t = start; t < n8; t += stride) {
        int e = t * 8;
        const float* src = (e < nu) ? (u + e) : (it + (e - nu));
        float4 x = *(const float4*)src;
        float4 y = *(const float4*)(src + 4);
        H8 v;
        v.h[0] = (_Float16)x.x; v.h[1] = (_Float16)x.y;
        v.h[2] = (_Float16)x.z; v.h[3] = (_Float16)x.w;
        v.h[4] = (_Float16)y.x; v.h[5] = (_Float16)y.y;
        v.h[6] = (_Float16)y.z; v.h[7] = (_Float16)y.w;
        ((uint4*)o)[t] = v.u;
    }
}

// ---------------- P1a (coarse hist) + fused f32->f16 conv (sepEmb mode) ----------------

__global__ void p1a_conv(const int* __restrict__ row, int E, int NB,
                         int* __restrict__ counts,
                         const float* __restrict__ u, const float* __restrict__ it,
                         int nu, int ntot, unsigned short* __restrict__ o, int NBLK) {
    __shared__ int h[MAXNB];
    int blk = blockIdx.x;
    if (blk < NBLK) {
        for (int b = threadIdx.x; b < NB; b += 256) h[b] = 0;
        __syncthreads();
        int base = blk * CHUNK;
        int end = min(base + CHUNK, E);
        int vend = base + ((end - base) & ~3);
        for (int i = base + threadIdx.x * 4; i < vend; i += 1024) {
            int4 r = *(const int4*)(row + i);
            atomicAdd(&h[r.x >> BSHIFT], 1);
            atomicAdd(&h[r.y >> BSHIFT], 1);
            atomicAdd(&h[r.z >> BSHIFT], 1);
            atomicAdd(&h[r.w >> BSHIFT], 1);
        }
        for (int i = vend + threadIdx.x; i < end; i += 256) atomicAdd(&h[row[i] >> BSHIFT], 1);
        __syncthreads();
        for (int b = threadIdx.x; b < NB; b += 256) counts[(size_t)blk * NB + b] = h[b];
    } else {
        int nConv = gridDim.x - NBLK;
        convBody(u, it, nu, ntot, o, (blk - NBLK) * 256 + threadIdx.x, nConv * 256);
    }
}

// fallback standalone conv (overlay layout)
__global__ void conv2_k(const float* __restrict__ u, const float* __restrict__ it,
                        int nu, int ntot, unsigned short* __restrict__ o) {
    convBody(u, it, nu, ntot, o, blockIdx.x * blockDim.x + threadIdx.x,
             gridDim.x * blockDim.x);
}

__global__ void p1b_scan(int* __restrict__ counts, int NBLK, int NB,
                         int* __restrict__ bucketTotal) {
    int b = blockIdx.x, t = threadIdx.x;
    __shared__ int sh[256];
    int v[8];
    int run = 0;
#pragma unroll
    for (int i = 0; i < 8; i++) {
        int idx = t * 8 + i;
        int c = (idx < NBLK) ? counts[(size_t)idx * NB + b] : 0;
        v[i] = run;  // exclusive within thread
        run += c;
    }
    int inc = blockScan256(run, sh);
    int excl = inc - run;
#pragma unroll
    for (int i = 0; i < 8; i++) {
        int idx = t * 8 + i;
        if (idx < NBLK) counts[(size_t)idx * NB + b] = v[i] + excl;
    }
    if (t == 255) bucketTotal[b] = sh[255];
}

__global__ void p_scan_tot(const int* __restrict__ bucketTotal, int NB,
                           int* __restrict__ bucketStart) {
    int t = threadIdx.x;
    __shared__ int sh[256];
    int v[8];
    int run = 0;
#pragma unroll
    for (int i = 0; i < 8; i++) {
        int idx = t * 8 + i;
        int c = (idx < NB) ? bucketTotal[idx] : 0;
        v[i] = run;
        run += c;
    }
    int inc = blockScan256(run, sh);
    int excl = inc - run;
#pragma unroll
    for (int i = 0; i < 8; i++) {
        int idx = t * 8 + i;
        if (idx < NB) bucketStart[idx] = v[i] + excl;
    }
    if (t == 255) bucketStart[NB] = sh[255];
}

// P1c: scatter into 64KB LDS stage grouped by bucket, then COALESCED writeback of
// each bucket's contiguous run. Raw per-(chunk,bucket) counts recovered from the
// scanned counts matrix: raw = counts[blk+1][b] - counts[blk][b] (last: bucketTotal).
__global__ void p1c_scatter(const int* __restrict__ row, const int* __restrict__ col,
                            const float* __restrict__ vals, int E, int NB, int NBLK,
                            const int* __restrict__ counts, const int* __restrict__ bucketTotal,
                            const int* __restrict__ bucketStart, int2* __restrict__ bdata) {
    __shared__ int2 stage[CHUNK];
    __shared__ int cur[MAXNB];
    __shared__ int rawcnt[MAXNB];
    __shared__ int sh[256];
    int blk = blockIdx.x, t = threadIdx.x;
    int base = blk * CHUNK;
    int end = min(base + CHUNK, E);
    // local exclusive scan of raw counts -> stage offsets
    int v[2];
    int run = 0;
#pragma unroll
    for (int i = 0; i < 2; i++) {
        int b = t * 2 + i;
        int c = 0;
        if (b < NB) {
            int s0 = counts[(size_t)blk * NB + b];
            int s1 = (blk + 1 < NBLK) ? counts[(size_t)(blk + 1) * NB + b] : bucketTotal[b];
            c = s1 - s0;
            rawcnt[b] = c;
        }
        v[i] = run;
        run += c;
    }
    int inc = blockScan256(run, sh);
    int excl = inc - run;
#pragma unroll
    for (int i = 0; i < 2; i++) {
        int b = t * 2 + i;
        if (b < NB) cur[b] = excl + v[i];
    }
    __syncthreads();
    // scatter edges into the LDS stage (bucket-grouped)
    int vend = base + ((end - base) & ~3);
    for (int i = base + t * 4; i < vend; i += 1024) {
        int4 r = *(const int4*)(row + i);
        int4 c = *(const int4*)(col + i);
        float4 w = *(const float4*)(vals + i);
        int p0 = atomicAdd(&cur[r.x >> BSHIFT], 1);
        int p1 = atomicAdd(&cur[r.y >> BSHIFT], 1);
        int p2 = atomicAdd(&cur[r.z >> BSHIFT], 1);
        int p3 = atomicAdd(&cur[r.w >> BSHIFT], 1);
        stage[p0] = make_int2(((r.x & (RPB - 1)) << 20) | c.x, __float_as_int(w.x));
        stage[p1] = make_int2(((r.y & (RPB - 1)) << 20) | c.y, __float_as_int(w.y));
        stage[p2] = make_int2(((r.z & (RPB - 1)) << 20) | c.z, __float_as_int(w.z));
        stage[p3] = make_int2(((r.w & (RPB - 1)) << 20) | c.w, __float_as_int(w.w));
    }
    for (int i = vend + t; i < end; i += 256) {
        int r = row[i];
        int p = atomicAdd(&cur[r >> BSHIFT], 1);
        stage[p] = make_int2(((r & (RPB - 1)) << 20) | col[i], __float_as_int(vals[i]));
    }
    __syncthreads();
    // coalesced writeback: wave per bucket round-robin; each bucket is one
    // contiguous run both in LDS and in global.
    int wv = t >> 6, lane = t & 63;
    for (int b = wv; b < NB; b += 4) {
        int cnt = rawcnt[b];
        int lo = cur[b] - cnt;
        int gb = bucketStart[b] + counts[(size_t)blk * NB + b];
        for (int i = lane; i < cnt; i += 64)
            bdata[gb + i] = stage[lo + i];
    }
}

// P2: per-bucket regroup by exact row into PADDED rows (pads = colOff 0, val 0).
// pairs.x stores col*128 (byte offset). Only pad slots are filled post-scatter.
__global__ void p2_group(const int2* __restrict__ bdata, const int* __restrict__ bucketStart,
                         int NB, int N, int padSlop,
                         int* __restrict__ rowStart, int* __restrict__ rowLen,
                         int2* __restrict__ pairs) {
    __shared__ int hist[RPB];
    __shared__ int sh[256];
    __shared__ int cur[RPB];
    int b = blockIdx.x, t = threadIdx.x;
    int s0 = bucketStart[b], s1 = bucketStart[b + 1];
    int pbase = s0 + b * padSlop;
    for (int i = t; i < RPB; i += 256) hist[i] = 0;
    __syncthreads();
    for (int i = s0 + t; i < s1; i += 256)
        atomicAdd(&hist[(bdata[i].x >> 20) & (RPB - 1)], 1);
    __syncthreads();
    int v[4];
    int run = 0;
#pragma unroll
    for (int i = 0; i < 4; i++) {
        int h = hist[t * 4 + i];
        int hp = (h + PADMASK) & ~PADMASK;
        v[i] = run;  // exclusive within thread
        run += hp;
    }
    int inc = blockScan256(run, sh);
    int excl = inc - run;
#pragma unroll
    for (int i = 0; i < 4; i++) {
        int r = (b << BSHIFT) + t * 4 + i;
        int st = excl + v[i];
        if (r < N) {
            int h = hist[t * 4 + i];
            rowStart[r] = pbase + st;
            rowLen[r] = (h + PADMASK) & ~PADMASK;
        }
        cur[t * 4 + i] = st;
    }
    __syncthreads();
    for (int i = s0 + t; i < s1; i += 256) {
        int2 e = bdata[i];
        int rl = (e.x >> 20) & (RPB - 1);
        int pos = atomicAdd(&cur[rl], 1);
        pairs[pbase + pos] = make_int2((e.x & 0xFFFFF) << 7, e.y);
    }
    __syncthreads();
#pragma unroll
    for (int i = 0; i < 4; i++) {
        int h = hist[t * 4 + i];
        int hp = (h + PADMASK) & ~PADMASK;
        int st = excl + v[i];
        for (int p = st + h; p < st + hp; p++)
            pairs[pbase + p] = make_int2(0, 0);
    }
}

// ---------------- layer-1 SpMM: wave per row, 8 edge-groups x 8 dim-octs ----------------
// f16 storage + (float)h * v accumulation -> v_fma_mix_f32 (no unpack ops).

__global__ void spmm1_k(const unsigned short* __restrict__ emb16,
                        const int* __restrict__ rowStart, const int* __restrict__ rowLen,
                        const int2* __restrict__ pairs,
                        int n_total, unsigned short* __restrict__ e1) {
    int wave = (blockIdx.x * blockDim.x + threadIdx.x) >> 6;
    int lane = threadIdx.x & 63;
    if (wave >= n_total) return;
    int eg = lane >> 3, dp = lane & 7;
    unsigned off0 = dp * 16u;
    const char* base = (const char*)emb16;
    int len = rowLen[wave];
    const int2* pp = pairs + rowStart[wave];
    float aA[8] = {0.f, 0.f, 0.f, 0.f, 0.f, 0.f, 0.f, 0.f};
    float aB[8] = {0.f, 0.f, 0.f, 0.f, 0.f, 0.f, 0.f, 0.f};
    int k = 0;
    for (; k + 16 <= len; k += 16) {
        int4 q = *(const int4*)(pp + k + 2 * eg);
        H8 g0, g1;
        g0.u = *(const uint4*)(base + ((unsigned)q.x + off0));
        g1.u = *(const uint4*)(base + ((unsigned)q.z + off0));
        float v0 = __int_as_float(q.y), v1 = __int_as_float(q.w);
#pragma unroll
        for (int i = 0; i < 8; i++) aA[i] += (float)g0.h[i] * v0;
#pragma unroll
        for (int i = 0; i < 8; i++) aB[i] += (float)g1.h[i] * v1;
    }
    if (k < len) {
        int2 p = pp[k + eg];
        H8 g0;
        g0.u = *(const uint4*)(base + ((unsigned)p.x + off0));
        float v0 = __int_as_float(p.y);
#pragma unroll
        for (int i = 0; i < 8; i++) aA[i] += (float)g0.h[i] * v0;
    }
    float s[8];
#pragma unroll
    for (int i = 0; i < 8; i++) s[i] = aA[i] + aB[i];
#pragma unroll
    for (int m = 8; m <= 32; m <<= 1) {
#pragma unroll
        for (int i = 0; i < 8; i++) s[i] += __shfl_xor(s[i], m);
    }
    if (eg == 0) {
        H8 o;
#pragma unroll
        for (int i = 0; i < 8; i++) o.h[i] = (_Float16)s[i];
        *(uint4*)(e1 + (size_t)wave * DIM + dp * 8) = o.u;
    }
}

// ---------------- fused layer-2 + gather + dot epilogue ----------------

__global__ void final_k(const float* __restrict__ emb_user, const float* __restrict__ emb_item,
                        int n_user, const unsigned short* __restrict__ e1,
                        const int* __restrict__ rowStart, const int* __restrict__ rowLen,
                        const int2* __restrict__ pairs,
                        const int* __restrict__ u_nodes, const int* __restrict__ p_nodes,
                        const int* __restrict__ n_nodes, int B, float* __restrict__ out) {
    int wave = (blockIdx.x * blockDim.x + threadIdx.x) >> 6;
    int lane = threadIdx.x & 63;
    if (wave >= B) return;
    int eg = lane >> 4, dp = lane & 15;
    unsigned off0 = dp * 8u;
    const char* base = (const char*)e1;
    int nid[3] = {u_nodes[wave], p_nodes[wave], n_nodes[wave]};
    float l[3][4];
#pragma unroll
    for (int j = 0; j < 3; j++) {
        int r = nid[j];
        const float* base0 = (r < n_user) ? (emb_user + (size_t)r * DIM)
                                          : (emb_item + (size_t)(r - n_user) * DIM);
        float4 l0 = *(const float4*)(base0 + dp * 4);
        H4 t1;
        t1.u = *(const uint2*)(e1 + (size_t)r * DIM + dp * 4);
        float acc[4];
        acc[0] = l0.x + (float)t1.h[0];
        acc[1] = l0.y + (float)t1.h[1];
        acc[2] = l0.z + (float)t1.h[2];
        acc[3] = l0.w + (float)t1.h[3];
        int len = rowLen[r];
        const int2* pp = pairs + rowStart[r];
        float a0[4] = {0.f, 0.f, 0.f, 0.f}, a1[4] = {0.f, 0.f, 0.f, 0.f};
        float a2[4] = {0.f, 0.f, 0.f, 0.f}, a3[4] = {0.f, 0.f, 0.f, 0.f};
        int k = 0;
        for (; k + 16 <= len; k += 16) {
            int4 q0 = *(const int4*)(pp + k + 2 * eg);
            int4 q1 = *(const int4*)(pp + k + 8 + 2 * eg);
            H4 g0, g1, g2, g3;
            g0.u = *(const uint2*)(base + ((unsigned)q0.x + off0));
            g1.u = *(const uint2*)(base + ((unsigned)q0.z + off0));
            g2.u = *(const uint2*)(base + ((unsigned)q1.x + off0));
            g3.u = *(const uint2*)(base + ((unsigned)q1.z + off0));
            float v0 = __int_as_float(q0.y), v1 = __int_as_float(q0.w);
            float v2 = __int_as_float(q1.y), v3 = __int_as_float(q1.w);
#pragma unroll
            for (int i = 0; i < 4; i++) {
                a0[i] += (float)g0.h[i] * v0;
                a1[i] += (float)g1.h[i] * v1;
                a2[i] += (float)g2.h[i] * v2;
                a3[i] += (float)g3.h[i] * v3;
            }
        }
        for (; k < len; k += 8) {
            int4 q0 = *(const int4*)(pp + k + 2 * eg);
            H4 g0, g1;
            g0.u = *(const uint2*)(base + ((unsigned)q0.x + off0));
            g1.u = *(const uint2*)(base + ((unsigned)q0.z + off0));
            float v0 = __int_as_float(q0.y), v1 = __int_as_float(q0.w);
#pragma unroll
            for (int i = 0; i < 4; i++) {
                a0[i] += (float)g0.h[i] * v0;
                a1[i] += (float)g1.h[i] * v1;
            }
        }
        float s[4];
#pragma unroll
        for (int i = 0; i < 4; i++) s[i] = (a0[i] + a1[i]) + (a2[i] + a3[i]);
#pragma unroll
        for (int i = 0; i < 4; i++) {
            s[i] += __shfl_xor(s[i], 16);
            s[i] += __shfl_xor(s[i], 32);
        }
#pragma unroll
        for (int i = 0; i < 4; i++) l[j][i] = (acc[i] + s[i]) * (1.0f / 3.0f);
    }
    float ps = l[0][0] * l[1][0] + l[0][1] * l[1][1] + l[0][2] * l[1][2] + l[0][3] * l[1][3];
    float ns = l[0][0] * l[2][0] + l[0][1] * l[2][1] + l[0][2] * l[2][2] + l[0][3] * l[2][3];
    ps += __shfl_xor(ps, 1); ns += __shfl_xor(ns, 1);
    ps += __shfl_xor(ps, 2); ns += __shfl_xor(ns, 2);
    ps += __shfl_xor(ps, 4); ns += __shfl_xor(ns, 4);
    ps += __shfl_xor(ps, 8); ns += __shfl_xor(ns, 8);
    if (lane == 0) {
        out[wave] = ps;
        out[B + wave] = ns;
    }
}

extern "C" void kernel_launch(void* const* d_in, const int* in_sizes, int n_in,
                              void* d_out, int out_size, void* d_ws, size_t ws_size,
                              hipStream_t stream) {
    const float* emb_user = (const float*)d_in[0];
    const float* emb_item = (const float*)d_in[1];
    const float* gvals    = (const float*)d_in[2];
    const int*   grow     = (const int*)d_in[3];
    const int*   gcol     = (const int*)d_in[4];
    const int*   unodes   = (const int*)d_in[5];
    const int*   pnodes   = (const int*)d_in[6];
    const int*   nnodes   = (const int*)d_in[7];
    float* out = (float*)d_out;

    int n_user = in_sizes[0] / DIM;
    int n_item = in_sizes[1] / DIM;
    int N = n_user + n_item;
    int E = in_sizes[2];
    int B = in_sizes[5];
    int NB = (N + RPB - 1) >> BSHIFT;
    int NBLK = (E + CHUNK - 1) / CHUNK;
    int padSlop = RPB * PADMASK;

    auto align256 = [](size_t x) { return (x + 255) & ~(size_t)255; };
    size_t embBytes = (size_t)N * DIM * 2;
    size_t countsBytes = (size_t)NBLK * NB * 4;
    size_t bdataBytes = (size_t)E * 8;
    size_t regionABytes = countsBytes > embBytes ? countsBytes : embBytes;  // counts / e1
    size_t pairsBytes = ((size_t)E + (size_t)NB * padSlop) * 8;
    size_t fixedBytes = align256((size_t)N * 4) * 2 + align256((size_t)MAXNB * 4) +
                        align256((size_t)(MAXNB + 1) * 4) + align256(pairsBytes) +
                        align256(regionABytes);
    // preferred: emb16 separate from bdata -> conv fused into p1a (before bdata exists)
    bool sepEmb = fixedBytes + align256(bdataBytes) + align256(embBytes) <= ws_size;

    char* ws = (char*)d_ws;
    size_t off = 0;
    auto alloc = [&](size_t bytes) -> void* {
        void* p = ws + off;
        off = (off + bytes + 255) & ~(size_t)255;
        return p;
    };
    int*  rowStart    = (int*)alloc((size_t)N * 4);
    int*  rowLen      = (int*)alloc((size_t)N * 4);
    int*  bucketTotal = (int*)alloc((size_t)MAXNB * 4);
    int*  bucketStart = (int*)alloc((size_t)(MAXNB + 1) * 4);
    int2* pairs       = (int2*)alloc(pairsBytes);
    int2* bdata;
    unsigned short* emb16;
    if (sepEmb) {
        bdata = (int2*)alloc(bdataBytes);
        emb16 = (unsigned short*)alloc(embBytes);
    } else {
        char* regionB = (char*)alloc(bdataBytes > embBytes ? bdataBytes : embBytes);
        bdata = (int2*)regionB;            // dead after p2
        emb16 = (unsigned short*)regionB;  // written after p2 (overlay)
    }
    char* regionA = (char*)alloc(regionABytes);
    int*            counts = (int*)regionA;  // dead after p1c
    unsigned short* e1     = (unsigned short*)regionA;
    (void)n_in; (void)out_size;

    // CSR build via two-level counting sort (no global atomics)
    int nConv = sepEmb ? CONVB : 0;
    p1a_conv<<<NBLK + nConv, 256, 0, stream>>>(grow, E, NB, counts,
                                               emb_user, emb_item, n_user * DIM, N * DIM,
                                               emb16, NBLK);
    p1b_scan<<<NB, 256, 0, stream>>>(counts, NBLK, NB, bucketTotal);
    p_scan_tot<<<1, 256, 0, stream>>>(bucketTotal, NB, bucketStart);
    p1c_scatter<<<NBLK, 256, 0, stream>>>(grow, gcol, gvals, E, NB, NBLK,
                                          counts, bucketTotal, bucketStart, bdata);
    p2_group<<<NB, 256, 0, stream>>>(bdata, bucketStart, NB, N, padSlop,
                                     rowStart, rowLen, pairs);
    if (!sepEmb)  // overlay layout: pack after bdata is dead
        conv2_k<<<2048, 256, 0, stream>>>(emb_user, emb_item, n_user * DIM, N * DIM, emb16);

    // layer-1 SpMM over all rows (e1 overlays dead counts)
    spmm1_k<<<(N + 3) / 4, 256, 0, stream>>>(emb16, rowStart, rowLen, pairs, N, e1);
    // fused layer-2 + gather + dots
    final_k<<<(B + 3) / 4, 256, 0, stream>>>(emb_user, emb_item, n_user, e1,
                                             rowStart, rowLen, pairs,
                                             unodes, pnodes, nnodes, B, out);
}